// Round 12
// baseline (194.538 us; speedup 1.0000x reference)
//
#include <hip/hip_runtime.h>
#include <hip/hip_bf16.h>

// SineLayer: y[b,o] = sum_{i,d} sin(w_d*x[b,i]+p_d) * (scale_d*c[o,i,d]) + offs[o]
// GEMM: M=32768, N=512, K=4096, bf16 MFMA 16x16x32.
// R12: ZERO-BARRIER design. Each wave is a self-contained pipeline:
//  - A fragments computed in-register (32 sins/lane/step, cvt_pk packed).
//  - B: wave glls its own 8KB slice into a private 2-slot LDS ring; the only
//    sync is s_waitcnt vmcnt(16) (same-wave issue-order arithmetic).
// BM=64 x BN=512, 4 waves (wave = 64 rows x 128 cols), 2 blocks/CU.

#define BATCH 32768
#define NIN   256
#define NOUT  512
#define DDIM  16
#define BM    64
#define BN    512
#define NKS   128              // K-slices of 32 (K = 4096)
#define BSLICE 32768           // bytes per cb K-slice (512 rows x 64 B)
#define EPSV  1e-8f
#define INV2PI 0.15915494309189535f

typedef short  bf16x8 __attribute__((ext_vector_type(8)));
typedef float  f32x4  __attribute__((ext_vector_type(4)));

static __device__ __forceinline__ ushort f2bf(float f) {
  union { __hip_bfloat16 h; ushort u; } cv;
  cv.h = __float2bfloat16(f);
  return cv.u;
}

static __device__ __forceinline__ uint cvt_pk(float lo, float hi) {
  uint r;
  asm("v_cvt_pk_bf16_f32 %0, %1, %2" : "=v"(r) : "v"(lo), "v"(hi));
  return r;
}

// ---------------------------------------------------------------------------
// Prep (= R11): cb slice layout with unit-swizzle. Slice ks = 32KB: row o at
// o*64; 16B unit h at (h ^ ((o>>1)&3))*16 within the row. Linear gll copy
// yields the swizzled LDS image. offs[o] = bias[o] + sum mu*scale*c.
// ---------------------------------------------------------------------------
__global__ __launch_bounds__(256) void prep_kernel(
    const float* __restrict__ omega, const float* __restrict__ phase,
    const float* __restrict__ c_basis, const float* __restrict__ bias,
    ushort* __restrict__ cb, float* __restrict__ offs)
{
  __shared__ float s_scale[DDIM];
  __shared__ float s_musc[DDIM];
  __shared__ float s_red[4];

  const int o = blockIdx.x;
  const int t = threadIdx.x;

  if (t < DDIM) {
    float w = omega[t];
    float p = phase[t];
    float mu  = expf(-0.5f * w * w) * sinf(p);
    float var = 0.5f * (1.0f - expf(-2.0f * w * w) * cosf(2.0f * p)) - mu * mu;
    float sd  = sqrtf(fmaxf(var, 0.0f));
    float sc  = 1.0f / (sd + EPSV);
    s_scale[t] = sc;
    s_musc[t]  = mu * sc;
  }
  __syncthreads();

  const float* cp = c_basis + ((size_t)o * NIN + t) * DDIM;
  float cv[DDIM];
  {
    const float4* cp4 = (const float4*)cp;
    float4 a = cp4[0], b = cp4[1], c = cp4[2], d = cp4[3];
    cv[0]=a.x; cv[1]=a.y; cv[2]=a.z; cv[3]=a.w;
    cv[4]=b.x; cv[5]=b.y; cv[6]=b.z; cv[7]=b.w;
    cv[8]=c.x; cv[9]=c.y; cv[10]=c.z; cv[11]=c.w;
    cv[12]=d.x; cv[13]=d.y; cv[14]=d.z; cv[15]=d.w;
  }

  float partial = 0.0f;
  uint pk[8];
#pragma unroll
  for (int d = 0; d < DDIM; d += 2) {
    partial += cv[d] * s_musc[d] + cv[d+1] * s_musc[d+1];
    ushort u0 = f2bf(cv[d]   * s_scale[d]);
    ushort u1 = f2bf(cv[d+1] * s_scale[d+1]);
    pk[d >> 1] = (uint)u0 | ((uint)u1 << 16);
  }

  {
    const int ks = t >> 1;
    const int h0 = (t & 1) * 2;          // units h0, h0+1
    const int fo = (o >> 1) & 3;
    char* rowp = (char*)cb + (size_t)ks * BSLICE + o * 64;
    *(uint4*)(rowp + ((h0    ) ^ fo) * 16) = make_uint4(pk[0], pk[1], pk[2], pk[3]);
    *(uint4*)(rowp + ((h0 + 1) ^ fo) * 16) = make_uint4(pk[4], pk[5], pk[6], pk[7]);
  }

#pragma unroll
  for (int off = 32; off > 0; off >>= 1) partial += __shfl_down(partial, off, 64);
  if ((t & 63) == 0) s_red[t >> 6] = partial;
  __syncthreads();
  if (t == 0) offs[o] = bias[o] + s_red[0] + s_red[1] + s_red[2] + s_red[3];
}

// ---------------------------------------------------------------------------
// GEMM: 64x512 tile, 256 threads (4 waves, wave = 64 rows x 128 cols).
// LDS: per-wave private ring, 2 slots x 8KB -> 64 KB/block, 2 blocks/CU.
// Per step s (per wave, NO barriers):
//   gll B(s+1) -> slot (s+1)&1 [8 ops]; load x(s+1) float2 x4;
//   s_waitcnt vmcnt(16)  [drains B(s)];
//   sins -> af[0..3] in-register; ds_read bfr[0..7] from slot s&1; 32 MFMA.
// ---------------------------------------------------------------------------
__global__ __launch_bounds__(256, 2) void gemm_kernel(
    const float* __restrict__ x, const float* __restrict__ omega,
    const float* __restrict__ phase, const ushort* __restrict__ cb,
    const float* __restrict__ offs, float* __restrict__ out)
{
  extern __shared__ char lds[];   // 4 waves x 16 KB private rings

  const int t    = threadIdx.x;
  const int lane = t & 63;
  const int wn   = t >> 6;         // 0..3 : wave's 128-col slice
  const int row0 = blockIdx.x * BM;

  const int hi  = lane >> 4;       // 0..3
  const int l15 = lane & 15;
  const int hu  = (hi ^ ((l15 >> 1) & 3)) * 16;  // swizzled unit byte offset

  // per-lane omega/phase for d = (hi&1)*8 + j, revolutions folded in
  float wl[8], pl[8];
  {
    const int dbase = (hi & 1) * 8;
#pragma unroll
    for (int j = 0; j < 8; ++j) {
      wl[j] = omega[dbase + j] * INV2PI;
      pl[j] = phase[dbase + j] * INV2PI;
    }
  }

  // x row pointers for the 4 m-fragments (rows m*16 + l15)
  const float* xp0 = x + (size_t)(row0 + 0 * 16 + l15) * NIN;
  const float* xp1 = x + (size_t)(row0 + 1 * 16 + l15) * NIN;
  const float* xp2 = x + (size_t)(row0 + 2 * 16 + l15) * NIN;
  const float* xp3 = x + (size_t)(row0 + 3 * 16 + l15) * NIN;

  f32x4 acc[4][8];
#pragma unroll
  for (int m = 0; m < 4; ++m)
#pragma unroll
    for (int n = 0; n < 8; ++n) acc[m][n] = (f32x4){0.f, 0.f, 0.f, 0.f};

  char* ldsW = lds + wn * 16384;   // this wave's private ring

#define GLL(s_, d_) __builtin_amdgcn_global_load_lds(                          \
      (const __attribute__((address_space(1))) void*)(s_),                     \
      (__attribute__((address_space(3))) void*)(d_), 16, 0, 0)

  // 8 gll: this wave's 8KB of B slice ks_ -> ring slot slot_
#define ISSUE_B(ks_, slot_)                                                    \
  {                                                                            \
    const char* src = (const char*)cb + (size_t)(ks_) * BSLICE                 \
                      + wn * 8192 + lane * 16;                                 \
    char* dst = ldsW + (slot_) * 8192;                                         \
    GLL(src, dst);               GLL(src + 1024, dst + 1024);                  \
    GLL(src + 2048, dst + 2048); GLL(src + 3072, dst + 3072);                  \
    GLL(src + 4096, dst + 4096); GLL(src + 5120, dst + 5120);                  \
    GLL(src + 6144, dst + 6144); GLL(src + 7168, dst + 7168);                  \
  }

  // 4 float2 x-prefetch for step s_ (cols 2*s_, 2*s_+1)
#define XLOAD(XV_, s_)                                                         \
    XV_[0] = *(const float2*)(xp0 + 2 * (s_));                                 \
    XV_[1] = *(const float2*)(xp1 + 2 * (s_));                                 \
    XV_[2] = *(const float2*)(xp2 + 2 * (s_));                                 \
    XV_[3] = *(const float2*)(xp3 + 2 * (s_));

  // in-register A fragment m: 8 sins for row m*16+l15, k = hi*8..+8
#define MAKE_AF(m_, XV_)                                                       \
  {                                                                            \
    float xx = (hi & 2) ? XV_[m_].y : XV_[m_].x;                               \
    uint w0 = cvt_pk(__builtin_amdgcn_sinf(fmaf(wl[0], xx, pl[0])),            \
                     __builtin_amdgcn_sinf(fmaf(wl[1], xx, pl[1])));           \
    uint w1 = cvt_pk(__builtin_amdgcn_sinf(fmaf(wl[2], xx, pl[2])),            \
                     __builtin_amdgcn_sinf(fmaf(wl[3], xx, pl[3])));           \
    uint w2 = cvt_pk(__builtin_amdgcn_sinf(fmaf(wl[4], xx, pl[4])),            \
                     __builtin_amdgcn_sinf(fmaf(wl[5], xx, pl[5])));           \
    uint w3 = cvt_pk(__builtin_amdgcn_sinf(fmaf(wl[6], xx, pl[6])),            \
                     __builtin_amdgcn_sinf(fmaf(wl[7], xx, pl[7])));           \
    uint2 lohi0 = make_uint2(w0, w1), lohi1 = make_uint2(w2, w3);              \
    af[m_] = __builtin_bit_cast(bf16x8,                                        \
              make_uint4(lohi0.x, lohi0.y, lohi1.x, lohi1.y));                 \
  }

  // One step: slot sl_ = s&1; uses x XU_ (loaded last step), loads XL_ (s+1).
#define BODY(s_, sl_, XU_, XL_)                                                \
  {                                                                            \
    const int ksn = ((s_) + 1 < NKS ? (s_) + 1 : NKS - 1);                     \
    ISSUE_B(ksn, (sl_) ^ 1)                                                    \
    XLOAD(XL_, ksn)                                                            \
    __builtin_amdgcn_sched_barrier(0);                                         \
    asm volatile("s_waitcnt vmcnt(16)" ::: "memory");                          \
    bf16x8 af[4];                                                              \
    MAKE_AF(0, XU_) MAKE_AF(1, XU_) MAKE_AF(2, XU_) MAKE_AF(3, XU_)            \
    const char* BsB = ldsW + (sl_) * 8192;                                     \
    bf16x8 bfr[8];                                                             \
    _Pragma("unroll")                                                          \
    for (int n = 0; n < 8; ++n)                                                \
      bfr[n] = *(const bf16x8*)(BsB + (n * 16 + l15) * 64 + hu);               \
    __builtin_amdgcn_s_setprio(1);                                             \
    _Pragma("unroll")                                                          \
    for (int m = 0; m < 4; ++m)                                                \
      _Pragma("unroll")                                                        \
      for (int n = 0; n < 8; ++n)                                              \
        acc[m][n] = __builtin_amdgcn_mfma_f32_16x16x32_bf16(af[m], bfr[n], acc[m][n], 0, 0, 0); \
    __builtin_amdgcn_s_setprio(0);                                             \
  }

  float2 xvA[4], xvB[4];

  // ---- prologue: B(0) -> slot0; x(0) ----
  ISSUE_B(0, 0)
  XLOAD(xvA, 0)

  for (int s = 0; s < NKS; s += 2) {
    BODY(s,     0, xvA, xvB)
    BODY(s + 1, 1, xvB, xvA)
  }

  // ---- epilogue: y = acc + offs[o] ----
#pragma unroll
  for (int n = 0; n < 8; ++n) {
    int col = wn * 128 + n * 16 + l15;
    float off = offs[col];
#pragma unroll
    for (int m = 0; m < 4; ++m) {
      int row = row0 + m * 16 + hi * 4;
      float* op = out + (size_t)row * NOUT + col;
#pragma unroll
      for (int j = 0; j < 4; ++j)
        op[(size_t)j * NOUT] = acc[m][n][j] + off;
    }
  }
}

// ---------------------------------------------------------------------------
extern "C" void kernel_launch(void* const* d_in, const int* in_sizes, int n_in,
                              void* d_out, int out_size, void* d_ws, size_t ws_size,
                              hipStream_t stream) {
  const float* x       = (const float*)d_in[0];
  const float* omega   = (const float*)d_in[1];
  const float* phase   = (const float*)d_in[2];
  const float* c_basis = (const float*)d_in[3];
  const float* bias    = (const float*)d_in[4];
  float* out = (float*)d_out;

  float*  offs = (float*)d_ws;
  ushort* cb   = (ushort*)((char*)d_ws + 2048);

  hipFuncSetAttribute((const void*)gemm_kernel,
                      hipFuncAttributeMaxDynamicSharedMemorySize, 65536);

  prep_kernel<<<NOUT, 256, 0, stream>>>(omega, phase, c_basis, bias, cb, offs);
  gemm_kernel<<<BATCH / BM, 256, 65536, stream>>>(x, omega, phase, cb, offs, out);
}

// Round 13
// 127.600 us; speedup vs baseline: 1.5246x; 1.5246x over previous
//
#include <hip/hip_runtime.h>
#include <hip/hip_bf16.h>

// SineLayer: y[b,o] = sum_{i,d} sin(w_d*x[b,i]+p_d) * (scale_d*c[o,i,d]) + offs[o]
// GEMM: M=32768, N=512, K=4096, bf16 MFMA 16x16x32.
// R13: R7 base (best known, 139us) + cvt_pk pack + MFMA sandwich:
//   MFMA(kk0) ; [sins(kt+1) + A-write + B-issue(kt+1)] ; MFMA(kk1) ; CBAR(1).
// Staging VALU sits between the two MFMA blocks -> co-wave overlap fills pipes.

#define BATCH 32768
#define NIN   256
#define NOUT  512
#define DDIM  16
#define BM    128
#define BN    512
#define BK    64
#define NKT   ((NIN*DDIM)/BK)     // 64 K-steps
#define TILE_BYTES (BN*BK*2)      // 64 KB per kt pre-swizzled B tile
#define ABYTES (BM*BK*2)          // 16 KB per A buffer
#define BBYTES (BN*BK*2)          // 64 KB per B buffer
#define EPSV  1e-8f
#define INV2PI 0.15915494309189535f

typedef short  bf16x8 __attribute__((ext_vector_type(8)));
typedef float  f32x4  __attribute__((ext_vector_type(4)));

static __device__ __forceinline__ ushort f2bf(float f) {
  union { __hip_bfloat16 h; ushort u; } cv;
  cv.h = __float2bfloat16(f);
  return cv.u;
}

static __device__ __forceinline__ uint cvt_pk(float lo, float hi) {
  uint r;
  asm("v_cvt_pk_bf16_f32 %0, %1, %2" : "=v"(r) : "v"(lo), "v"(hi));
  return r;
}

static __device__ __forceinline__ float sgpr_f(float v) {
  return __builtin_bit_cast(float,
      __builtin_amdgcn_readfirstlane(__builtin_bit_cast(int, v)));
}

// ---------------------------------------------------------------------------
// Prep: cb[o,k] = bf16(scale_d * c[o,i,d]) as ONE pre-swizzled 512x64 tile per
// kt (byte = (r*128 + kloc*2) ^ ((r&7)<<4), r = o) so a LINEAR global_load_lds
// copy yields the swizzled LDS image. offs[o] = bias[o] + sum mu*scale*c.
// ---------------------------------------------------------------------------
__global__ __launch_bounds__(256) void prep_kernel(
    const float* __restrict__ omega, const float* __restrict__ phase,
    const float* __restrict__ c_basis, const float* __restrict__ bias,
    ushort* __restrict__ cb, float* __restrict__ offs)
{
  __shared__ float s_scale[DDIM];
  __shared__ float s_musc[DDIM];
  __shared__ float s_red[4];

  const int o = blockIdx.x;
  const int t = threadIdx.x;

  if (t < DDIM) {
    float w = omega[t];
    float p = phase[t];
    float mu  = expf(-0.5f * w * w) * sinf(p);
    float var = 0.5f * (1.0f - expf(-2.0f * w * w) * cosf(2.0f * p)) - mu * mu;
    float sd  = sqrtf(fmaxf(var, 0.0f));
    float sc  = 1.0f / (sd + EPSV);
    s_scale[t] = sc;
    s_musc[t]  = mu * sc;
  }
  __syncthreads();

  const float* cp = c_basis + ((size_t)o * NIN + t) * DDIM;
  float cv[DDIM];
  {
    const float4* cp4 = (const float4*)cp;
    float4 a = cp4[0], b = cp4[1], c = cp4[2], d = cp4[3];
    cv[0]=a.x; cv[1]=a.y; cv[2]=a.z; cv[3]=a.w;
    cv[4]=b.x; cv[5]=b.y; cv[6]=b.z; cv[7]=b.w;
    cv[8]=c.x; cv[9]=c.y; cv[10]=c.z; cv[11]=c.w;
    cv[12]=d.x; cv[13]=d.y; cv[14]=d.z; cv[15]=d.w;
  }

  float partial = 0.0f;
  uint pk[8];
#pragma unroll
  for (int d = 0; d < DDIM; d += 2) {
    partial += cv[d] * s_musc[d] + cv[d+1] * s_musc[d+1];
    ushort u0 = f2bf(cv[d]   * s_scale[d]);
    ushort u1 = f2bf(cv[d+1] * s_scale[d+1]);
    pk[d >> 1] = (uint)u0 | ((uint)u1 << 16);
  }

  {
    const int r   = o;               // 0..511
    const int kt  = t >> 2;
    const int swz = (r & 7) << 4;
    char* tile = (char*)cb + (size_t)kt * TILE_BYTES;
    int b0 = r * 128 + (t & 3) * 32;
    *(uint4*)(tile + ((b0     ) ^ swz)) = make_uint4(pk[0], pk[1], pk[2], pk[3]);
    *(uint4*)(tile + ((b0 + 16) ^ swz)) = make_uint4(pk[4], pk[5], pk[6], pk[7]);
  }

#pragma unroll
  for (int off = 32; off > 0; off >>= 1) partial += __shfl_down(partial, off, 64);
  if ((t & 63) == 0) s_red[t >> 6] = partial;
  __syncthreads();
  if (t == 0) offs[o] = bias[o] + s_red[0] + s_red[1] + s_red[2] + s_red[3];
}

// ---------------------------------------------------------------------------
// GEMM: 128x512 tile, BK=64, 512 threads (8 waves: 2m x 4n, wave = 64x128).
// LDS: A0[16K] A1[16K] B0[64K] B1[64K] = 160 KB.
// ---------------------------------------------------------------------------
__global__ __launch_bounds__(512, 2) void gemm_kernel(
    const float* __restrict__ x, const float* __restrict__ omega,
    const float* __restrict__ phase, const ushort* __restrict__ cb,
    const float* __restrict__ offs, float* __restrict__ out)
{
  extern __shared__ char lds[];

  const int t    = threadIdx.x;
  const int lane = t & 63;
  const int wid  = t >> 6;
  const int wm   = wid >> 2;       // 0..1
  const int wn   = wid & 3;        // 0..3
  const int row0 = blockIdx.x * BM;

  // uniform omega/phase in SGPRs (readfirstlane) -> zero VGPR cost
  float wv[DDIM], pv[DDIM];
#pragma unroll
  for (int d = 0; d < DDIM; ++d) {
    wv[d] = sgpr_f(omega[d] * INV2PI);
    pv[d] = sgpr_f(phase[d] * INV2PI);
  }

  f32x4 acc[4][8];
#pragma unroll
  for (int m = 0; m < 4; ++m)
#pragma unroll
    for (int n = 0; n < 8; ++n) acc[m][n] = (f32x4){0.f, 0.f, 0.f, 0.f};

  // A staging: thread t -> row t>>2 (0..127), i-slot t&3; 1 x -> 16 sins
  const int arow = t >> 2;
  const int acol = t & 3;
  const float* xbase = x + (size_t)(row0 + arow) * NIN + acol;
  const int aswz = (arow & 7) << 4;
  const int ab0  = arow * 128 + acol * 32;

  const int hi  = lane >> 4;       // 0..3
  const int l15 = lane & 15;

#define GLL(s_, d_) __builtin_amdgcn_global_load_lds(                          \
      (const __attribute__((address_space(1))) void*)(s_),                     \
      (__attribute__((address_space(3))) void*)(d_), 16, 0, 0)

  // 8 global_load_lds: 64 KB B-tile kt_ -> B buffer sb_ (compile-time sb_)
#define ISSUE_B(kt_, sb_)                                                      \
  {                                                                            \
    const char* src = (const char*)cb + (size_t)(kt_) * TILE_BYTES             \
                      + wid * 8192 + lane * 16;                                \
    char* dst = lds + 32768 + (sb_) * BBYTES + wid * 8192;                     \
    GLL(src, dst);                 GLL(src + 1024, dst + 1024);                \
    GLL(src + 2048, dst + 2048);   GLL(src + 3072, dst + 3072);                \
    GLL(src + 4096, dst + 4096);   GLL(src + 5120, dst + 5120);                \
    GLL(src + 6144, dst + 6144);   GLL(src + 7168, dst + 7168);                \
  }

  // 16 sins -> 8 packed bf16-pair words via v_cvt_pk_bf16_f32
#define SINS_ALL(xx_)                                                          \
    _Pragma("unroll")                                                          \
    for (int d = 0; d < DDIM; d += 2) {                                        \
      float s0 = __builtin_amdgcn_sinf(fmaf(wv[d],   (xx_), pv[d]));           \
      float s1 = __builtin_amdgcn_sinf(fmaf(wv[d+1], (xx_), pv[d+1]));         \
      pk[d >> 1] = cvt_pk(s0, s1);                                             \
    }

  // two swizzled ds_write_b128 of the packed sins into A buffer sb_
#define A_WRITE2(sb_)                                                          \
    *(uint4*)(lds + (sb_) * ABYTES + ((ab0     ) ^ aswz)) =                    \
        make_uint4(pk[0], pk[1], pk[2], pk[3]);                                \
    *(uint4*)(lds + (sb_) * ABYTES + ((ab0 + 16) ^ aswz)) =                    \
        make_uint4(pk[4], pk[5], pk[6], pk[7]);

  // one kk-half (32 MFMAs), B-frags in 4-reg chunks (spill-safe)
#define MFMA_HALF(mb_, kk_)                                                    \
  {                                                                            \
    const char* AsB = lds + (mb_) * ABYTES;                                    \
    const char* BsB = lds + 32768 + (mb_) * BBYTES;                            \
    bf16x8 af[4];                                                              \
    _Pragma("unroll")                                                          \
    for (int m = 0; m < 4; ++m) {                                              \
      int rr = wm * 64 + m * 16 + l15;                                         \
      af[m] = *(const bf16x8*)(AsB + ((rr*128 + (kk_)*64 + hi*16) ^ ((rr&7)<<4))); \
    }                                                                          \
    __builtin_amdgcn_s_setprio(1);                                             \
    _Pragma("unroll")                                                          \
    for (int nh = 0; nh < 2; ++nh) {                                           \
      bf16x8 bfr[4];                                                           \
      _Pragma("unroll")                                                        \
      for (int n4 = 0; n4 < 4; ++n4) {                                         \
        int rr = wn * 128 + (nh * 4 + n4) * 16 + l15;                          \
        bfr[n4] = *(const bf16x8*)(BsB + ((rr*128 + (kk_)*64 + hi*16) ^ ((rr&7)<<4))); \
      }                                                                        \
      _Pragma("unroll")                                                        \
      for (int m = 0; m < 4; ++m)                                              \
        _Pragma("unroll")                                                      \
        for (int n4 = 0; n4 < 4; ++n4)                                         \
          acc[m][nh * 4 + n4] = __builtin_amdgcn_mfma_f32_16x16x32_bf16(       \
              af[m], bfr[n4], acc[m][nh * 4 + n4], 0, 0, 0);                   \
    }                                                                          \
    __builtin_amdgcn_s_setprio(0);                                             \
  }

#define CBAR(vm_)                                                              \
  __builtin_amdgcn_sched_barrier(0);                                           \
  asm volatile("s_waitcnt vmcnt(" #vm_ ") lgkmcnt(0)" ::: "memory");           \
  __builtin_amdgcn_s_barrier();                                                \
  __builtin_amdgcn_sched_barrier(0);

  // Sandwich body: B-issue + x-prefetch, MFMA(kk0), [sins+A-write], MFMA(kk1).
  // Light fences pin the staging between the two MFMA halves.
#define BODY(kt_, mb_, sb_, XU_, XL_)                                          \
  {                                                                            \
    ISSUE_B(((kt_) + 1 < NKT ? (kt_) + 1 : NKT - 1), sb_);                     \
    XL_ = xbase[((kt_) + 2 < NKT ? (kt_) + 2 : NKT - 1) * 4];                  \
    __builtin_amdgcn_sched_barrier(0);                                         \
    MFMA_HALF(mb_, 0)                                                          \
    __builtin_amdgcn_sched_barrier(0);                                         \
    uint pk[8];                                                                \
    SINS_ALL(XU_)                                                              \
    A_WRITE2(sb_)                                                              \
    __builtin_amdgcn_sched_barrier(0);                                         \
    MFMA_HALF(mb_, 1)                                                          \
    CBAR(1)                                                                    \
  }

  // ---- prologue ----
  float xs0, xs1;
  {
    float xp = xbase[0];
    __builtin_amdgcn_sched_barrier(0);
    ISSUE_B(0, 0);
    __builtin_amdgcn_sched_barrier(0);
    xs1 = xbase[4];
    __builtin_amdgcn_sched_barrier(0);
    {
      uint pk[8];
      SINS_ALL(xp)
      A_WRITE2(0)
    }
    CBAR(1)                       // drains B(0)+x(0), keeps xs1 in flight
  }

  for (int kt = 0; kt < NKT; kt += 2) {
    BODY(kt,     0, 1, xs1, xs0)
    BODY(kt + 1, 1, 0, xs0, xs1)
  }

  // ---- epilogue: y = acc + offs[o] ----
#pragma unroll
  for (int n = 0; n < 8; ++n) {
    int col = wn * 128 + n * 16 + l15;
    float off = offs[col];
#pragma unroll
    for (int m = 0; m < 4; ++m) {
      int row = row0 + wm * 64 + m * 16 + hi * 4;
      float* op = out + (size_t)row * NOUT + col;
#pragma unroll
      for (int j = 0; j < 4; ++j)
        op[(size_t)j * NOUT] = acc[m][n][j] + off;
    }
  }
}

// ---------------------------------------------------------------------------
extern "C" void kernel_launch(void* const* d_in, const int* in_sizes, int n_in,
                              void* d_out, int out_size, void* d_ws, size_t ws_size,
                              hipStream_t stream) {
  const float* x       = (const float*)d_in[0];
  const float* omega   = (const float*)d_in[1];
  const float* phase   = (const float*)d_in[2];
  const float* c_basis = (const float*)d_in[3];
  const float* bias    = (const float*)d_in[4];
  float* out = (float*)d_out;

  float*  offs = (float*)d_ws;
  ushort* cb   = (ushort*)((char*)d_ws + 2048);

  hipFuncSetAttribute((const void*)gemm_kernel,
                      hipFuncAttributeMaxDynamicSharedMemorySize, 163840);

  prep_kernel<<<NOUT, 256, 0, stream>>>(omega, phase, c_basis, bias, cb, offs);
  gemm_kernel<<<BATCH / BM, 512, 163840, stream>>>(x, omega, phase, cb, offs, out);
}